// Round 13
// baseline (100.369 us; speedup 1.0000x reference)
//
#include <hip/hip_runtime.h>
#include <hip/hip_bf16.h>

// Problem constants (SelectSphereConv, graph level 6)
#define VN 40962
#define NG 10241          // groups of 4 vertices, one per block
#define LDA_B 1168        // A-tile row stride bytes (576*2 + 16 pad)
#define LDS_TOT 18688     // 16 rows x 1168 -- A-tile only
#define XT_BYTES (VN * 512)

typedef float f32x4 __attribute__((ext_vector_type(4)));
typedef __bf16 bf16x8 __attribute__((ext_vector_type(8)));

// ---------------------------------------------------------------------------
// Kernel 1: transpose x [256(t=b*64+c), V] f32 -> x_t [V, 256] bf16
// ---------------------------------------------------------------------------
__global__ __launch_bounds__(256) void k_transpose(const float* __restrict__ x,
                                                   __bf16* __restrict__ xt) {
    __shared__ __bf16 tile[64][65];
    const int v0 = blockIdx.x * 64;
    const int t0 = blockIdx.y * 64;
    const int lane = threadIdx.x & 63;
    const int sub = threadIdx.x >> 6;

#pragma unroll
    for (int r = 0; r < 16; ++r) {
        const int t = t0 + r * 4 + sub;
        const int v = v0 + lane;
        float val = (v < VN) ? x[(size_t)t * VN + v] : 0.f;   // coalesced
        tile[r * 4 + sub][lane] = (__bf16)val;
    }
    __syncthreads();
#pragma unroll
    for (int r = 0; r < 16; ++r) {
        const int vv = r * 4 + sub;
        const int v = v0 + vv;
        if (v < VN) xt[(size_t)v * 256 + t0 + lane] = tile[lane][vv];  // coalesced
    }
}

// ---------------------------------------------------------------------------
// Kernel 2: pre-swizzle conv_w into MFMA fragment order (layout symmetric for
//   A- or B-operand use; R1/R3-validated):
//   wf[((w*18+ks)*64 + lane)*8 + e] = conv_w[(w*16+(lane&15))*576
//                                            + ks*32 + (lane>>4)*8 + e]
// ---------------------------------------------------------------------------
__global__ __launch_bounds__(64) void k_wprep(const float* __restrict__ conv_w,
                                              __bf16* __restrict__ wf) {
    const int id = blockIdx.x;           // w*18 + ks, 0..71
    const int ks = id % 18;
    const int w  = id / 18;
    const int lane = threadIdx.x;        // 0..63
    const int o  = w * 16 + (lane & 15);
    const int kb = (lane >> 4) * 8;
    const float* wrow = conv_w + (size_t)o * 576 + ks * 32 + kb;
    bf16x8 f;
#pragma unroll
    for (int e = 0; e < 8; ++e) f[e] = (__bf16)wrow[e];
    *(bf16x8*)(wf + ((size_t)id * 64 + lane) * 8) = f;
}

// ---------------------------------------------------------------------------
// Kernel 3: fused gather + interpolate + conv. ONE group (4 vertices) per
//   block; LDS = A-tile only (18688 B -> 8-block/CU cap). Changes vs R12:
//   (a) ALL 36 gathers hoisted ahead of interp (gv[4][9], static indices,
//       36 loads in flight -- halves exposed gather latency);
//   (b) MFMA operands SWAPPED: acc = mfma(W_frag, A_tile, acc) so
//       D col = (vv,b), row = o -- R3's validated direct-store applies:
//       no C-LDS, no barriers 2/3, no epilogue. ONE barrier per block.
//   NO waves-per-EU hint (R8/R9: forcing -> spills).
// ---------------------------------------------------------------------------
__global__ __launch_bounds__(256) void k_fused(const __bf16* __restrict__ xt,
                                               const int* __restrict__ index,
                                               const float* __restrict__ itp_mat,
                                               const __bf16* __restrict__ wf,
                                               const float* __restrict__ conv_b,
                                               float* __restrict__ out) {
    __shared__ char smem[LDS_TOT];

    const int tid  = threadIdx.x;
    const int lane = tid & 63;
    const int w    = tid >> 6;      // batch b in phase 1; o-tile in MFMA
    const int l16  = lane & 15;
    const int g4   = lane >> 4;
    const int v0   = blockIdx.x * 4;

    // ---------------- phase 1: gather (all hoisted) + interpolate ----------
    // thread t = (b = w, c = lane); gathers xt[nb*256 + t] (2B, 128B/wave)
    float gv[4][9];
#pragma unroll
    for (int vv = 0; vv < 4; ++vv) {
        const int v  = v0 + vv;
        const int vm = (v < VN) ? v : VN - 1;           // clamp tail
        const int* idxv = index + (size_t)vm * 9;       // uniform -> s_load
#pragma unroll
        for (int k = 0; k < 9; ++k)
            gv[vv][k] = (float)xt[(size_t)idxv[k] * 256 + tid];
    }
#pragma unroll
    for (int vv = 0; vv < 4; ++vv) {
        const int v  = v0 + vv;
        const int vm = (v < VN) ? v : VN - 1;
        const float* am = itp_mat + (size_t)vm * 81;    // uniform -> s_load
        float s[9];
#pragma unroll
        for (int j = 0; j < 9; ++j) s[j] = 0.f;
#pragma unroll
        for (int k = 0; k < 9; ++k) {
            const float gk = gv[vv][k];
#pragma unroll
            for (int j = 0; j < 9; ++j) s[j] += gk * am[k * 9 + j];
        }
        __bf16* rowp = (__bf16*)(smem + (vv * 4 + w) * LDA_B) + lane * 9;
#pragma unroll
        for (int j = 0; j < 9; ++j) rowp[j] = (__bf16)s[j];
    }
    __syncthreads();   // the ONLY barrier: A-tile ready

    // ---------------- phase 2: MFMA (A = streamed W, B = itp tile) --------
    f32x4 acc = {0.f, 0.f, 0.f, 0.f};
    {
        const char* ar = smem + l16 * LDA_B + g4 * 16;  // B-frag: col=(vv,b)=l16
        const __bf16* wfp = wf + ((size_t)(w * 18) * 64 + lane) * 8;
#pragma unroll
        for (int ks = 0; ks < 18; ++ks) {
            bf16x8 a  = *(const bf16x8*)(ar + ks * 64);
            bf16x8 wb = *(const bf16x8*)(wfp + (size_t)ks * 512);
            acc = __builtin_amdgcn_mfma_f32_16x16x32_bf16(wb, a, acc, 0, 0, 0);
        }
    }

    // ---------------- direct store (R3-validated mapping) ----------------
    // D col = l16 = (vv = l16>>2, b = l16&3); D row = o = w*16 + g4*4 + r.
    {
        const int vvs = l16 >> 2;
        const int bs  = l16 & 3;
        const int v_s = v0 + vvs;
        const int o_b = w * 16 + g4 * 4;
        const f32x4 bias4 = *(const f32x4*)(conv_b + o_b);   // 16B-aligned
        if (v_s < VN) {
            float* ob = out + (size_t)(bs * 64 + o_b) * VN + v_s;
#pragma unroll
            for (int r = 0; r < 4; ++r)
                ob[(size_t)r * VN] = acc[r] + bias4[r];
        }
    }
}

// ---------------------------------------------------------------------------
extern "C" void kernel_launch(void* const* d_in, const int* in_sizes, int n_in,
                              void* d_out, int out_size, void* d_ws, size_t ws_size,
                              hipStream_t stream) {
    const float* x       = (const float*)d_in[0];
    const int*   index   = (const int*)d_in[1];
    const float* itp_mat = (const float*)d_in[2];
    const float* conv_w  = (const float*)d_in[3];
    const float* conv_b  = (const float*)d_in[4];
    float* out = (float*)d_out;

    __bf16* xt = (__bf16*)d_ws;                          // 20,972,544 B
    __bf16* wfrag = (__bf16*)((char*)d_ws + XT_BYTES);   // + 73,728 B

    dim3 tgrid((VN + 63) / 64, 4, 1);
    k_transpose<<<tgrid, 256, 0, stream>>>(x, xt);
    k_wprep<<<72, 64, 0, stream>>>(conv_w, wfrag);
    k_fused<<<NG, 256, 0, stream>>>(xt, index, itp_mat, wfrag, conv_b, out);
}

// Round 14
// 86.820 us; speedup vs baseline: 1.1561x; 1.1561x over previous
//
#include <hip/hip_runtime.h>
#include <hip/hip_bf16.h>

// Problem constants (SelectSphereConv, graph level 6)
#define VN 40962
#define NG 10241          // groups of 4 vertices, one per block
#define LDA_B 1168        // A-tile row stride bytes (576*2 + 16 pad)
#define LDS_TOT 18688     // 16 rows x 1168 -- A-tile only
#define XT_BYTES (VN * 512)

typedef float f32x4 __attribute__((ext_vector_type(4)));
typedef __bf16 bf16x8 __attribute__((ext_vector_type(8)));

// ---------------------------------------------------------------------------
// Kernel 1: transpose x [256(t=b*64+c), V] f32 -> x_t [V, 256] bf16
// ---------------------------------------------------------------------------
__global__ __launch_bounds__(256) void k_transpose(const float* __restrict__ x,
                                                   __bf16* __restrict__ xt) {
    __shared__ __bf16 tile[64][65];
    const int v0 = blockIdx.x * 64;
    const int t0 = blockIdx.y * 64;
    const int lane = threadIdx.x & 63;
    const int sub = threadIdx.x >> 6;

#pragma unroll
    for (int r = 0; r < 16; ++r) {
        const int t = t0 + r * 4 + sub;
        const int v = v0 + lane;
        float val = (v < VN) ? x[(size_t)t * VN + v] : 0.f;   // coalesced
        tile[r * 4 + sub][lane] = (__bf16)val;
    }
    __syncthreads();
#pragma unroll
    for (int r = 0; r < 16; ++r) {
        const int vv = r * 4 + sub;
        const int v = v0 + vv;
        if (v < VN) xt[(size_t)v * 256 + t0 + lane] = tile[lane][vv];  // coalesced
    }
}

// ---------------------------------------------------------------------------
// Kernel 2: pre-swizzle conv_w into MFMA fragment order (layout symmetric for
//   A- or B-operand use; R1/R3-validated):
//   wf[((w*18+ks)*64 + lane)*8 + e] = conv_w[(w*16+(lane&15))*576
//                                            + ks*32 + (lane>>4)*8 + e]
// ---------------------------------------------------------------------------
__global__ __launch_bounds__(64) void k_wprep(const float* __restrict__ conv_w,
                                              __bf16* __restrict__ wf) {
    const int id = blockIdx.x;           // w*18 + ks, 0..71
    const int ks = id % 18;
    const int w  = id / 18;
    const int lane = threadIdx.x;        // 0..63
    const int o  = w * 16 + (lane & 15);
    const int kb = (lane >> 4) * 8;
    const float* wrow = conv_w + (size_t)o * 576 + ks * 32 + kb;
    bf16x8 f;
#pragma unroll
    for (int e = 0; e < 8; ++e) f[e] = (__bf16)wrow[e];
    *(bf16x8*)(wf + ((size_t)id * 64 + lane) * 8) = f;
}

// ---------------------------------------------------------------------------
// Kernel 3: fused gather + interpolate + conv == R13 verbatim PLUS a
//   bijective XCD-aware block swizzle (m204 formula). Rationale: the CP
//   round-robins blockIdx across the 8 XCDs, so R13's adjacent 16B output
//   segments (adjacent v) land in DIFFERENT XCD L2s -> no L2 write-combining
//   -> partial-sector HBM writebacks with read-modify-write: WRITE 103MB and
//   ~60MB of RMW FETCH vs 42MB ideal (58% of all HBM traffic is overhead).
//   Swizzled, each XCD owns a contiguous v-range; its resident blocks span
//   ~2.5-4KB of consecutive v per out-row, so L2 assembles full 128B lines.
//   Also improves xt-gather / idx / itp_mat XCD-locality.
// ---------------------------------------------------------------------------
__global__ __launch_bounds__(256) void k_fused(const __bf16* __restrict__ xt,
                                               const int* __restrict__ index,
                                               const float* __restrict__ itp_mat,
                                               const __bf16* __restrict__ wf,
                                               const float* __restrict__ conv_b,
                                               float* __restrict__ out) {
    __shared__ char smem[LDS_TOT];

    const int tid  = threadIdx.x;
    const int lane = tid & 63;
    const int w    = tid >> 6;      // batch b in phase 1; o-tile in MFMA
    const int l16  = lane & 15;
    const int g4   = lane >> 4;

    // ---- bijective XCD swizzle: NG = 10241 = 8*1280 + 1 ----
    // xcd = bid & 7 (HW dispatch round-robin); XCD 0 owns groups [0,1281),
    // XCD k>=1 owns [1281+(k-1)*1280, ...+1280). Bijective on 0..10240.
    int g;
    {
        const int bid = blockIdx.x;
        const int xcd = bid & 7;
        const int idx = bid >> 3;
        g = (xcd == 0) ? idx : (1281 + (xcd - 1) * 1280 + idx);
    }
    const int v0 = g * 4;

    // ---------------- phase 1: gather (all hoisted) + interpolate ----------
    // thread t = (b = w, c = lane); gathers xt[nb*256 + t] (2B, 128B/wave)
    float gv[4][9];
#pragma unroll
    for (int vv = 0; vv < 4; ++vv) {
        const int v  = v0 + vv;
        const int vm = (v < VN) ? v : VN - 1;           // clamp tail
        const int* idxv = index + (size_t)vm * 9;       // uniform -> s_load
#pragma unroll
        for (int k = 0; k < 9; ++k)
            gv[vv][k] = (float)xt[(size_t)idxv[k] * 256 + tid];
    }
#pragma unroll
    for (int vv = 0; vv < 4; ++vv) {
        const int v  = v0 + vv;
        const int vm = (v < VN) ? v : VN - 1;
        const float* am = itp_mat + (size_t)vm * 81;    // uniform -> s_load
        float s[9];
#pragma unroll
        for (int j = 0; j < 9; ++j) s[j] = 0.f;
#pragma unroll
        for (int k = 0; k < 9; ++k) {
            const float gk = gv[vv][k];
#pragma unroll
            for (int j = 0; j < 9; ++j) s[j] += gk * am[k * 9 + j];
        }
        __bf16* rowp = (__bf16*)(smem + (vv * 4 + w) * LDA_B) + lane * 9;
#pragma unroll
        for (int j = 0; j < 9; ++j) rowp[j] = (__bf16)s[j];
    }
    __syncthreads();   // the ONLY barrier: A-tile ready

    // ---------------- phase 2: MFMA (A = streamed W, B = itp tile) --------
    f32x4 acc = {0.f, 0.f, 0.f, 0.f};
    {
        const char* ar = smem + l16 * LDA_B + g4 * 16;  // B-frag: col=(vv,b)=l16
        const __bf16* wfp = wf + ((size_t)(w * 18) * 64 + lane) * 8;
#pragma unroll
        for (int ks = 0; ks < 18; ++ks) {
            bf16x8 a  = *(const bf16x8*)(ar + ks * 64);
            bf16x8 wb = *(const bf16x8*)(wfp + (size_t)ks * 512);
            acc = __builtin_amdgcn_mfma_f32_16x16x32_bf16(wb, a, acc, 0, 0, 0);
        }
    }

    // ---------------- direct store (R3/R13-validated mapping) -------------
    // D col = l16 = (vv = l16>>2, b = l16&3); D row = o = w*16 + g4*4 + r.
    {
        const int vvs = l16 >> 2;
        const int bs  = l16 & 3;
        const int v_s = v0 + vvs;
        const int o_b = w * 16 + g4 * 4;
        const f32x4 bias4 = *(const f32x4*)(conv_b + o_b);   // 16B-aligned
        if (v_s < VN) {
            float* ob = out + (size_t)(bs * 64 + o_b) * VN + v_s;
#pragma unroll
            for (int r = 0; r < 4; ++r)
                ob[(size_t)r * VN] = acc[r] + bias4[r];
        }
    }
}

// ---------------------------------------------------------------------------
extern "C" void kernel_launch(void* const* d_in, const int* in_sizes, int n_in,
                              void* d_out, int out_size, void* d_ws, size_t ws_size,
                              hipStream_t stream) {
    const float* x       = (const float*)d_in[0];
    const int*   index   = (const int*)d_in[1];
    const float* itp_mat = (const float*)d_in[2];
    const float* conv_w  = (const float*)d_in[3];
    const float* conv_b  = (const float*)d_in[4];
    float* out = (float*)d_out;

    __bf16* xt = (__bf16*)d_ws;                          // 20,972,544 B
    __bf16* wfrag = (__bf16*)((char*)d_ws + XT_BYTES);   // + 73,728 B

    dim3 tgrid((VN + 63) / 64, 4, 1);
    k_transpose<<<tgrid, 256, 0, stream>>>(x, xt);
    k_wprep<<<72, 64, 0, stream>>>(conv_w, wfrag);
    k_fused<<<NG, 256, 0, stream>>>(xt, index, itp_mat, wfrag, conv_b, out);
}